// Round 1
// baseline (962.102 us; speedup 1.0000x reference)
//
#include <hip/hip_runtime.h>

#define HID 8
#define OBS_LEN 8
#define PRED_LEN 12
#define SCALE 4.4f

// Fast device math: v_exp_f32 + v_rcp_f32 (~1-2 ulp, far inside 2.6e-3 absmax threshold).
__device__ __forceinline__ float sigmoid_fast(float x) {
    // 1/(1+e^-x); x->-inf: exp->inf, rcp->0 (correct); x->+inf: rcp(1)=1 (correct)
    return __builtin_amdgcn_rcpf(1.0f + __expf(-x));
}
__device__ __forceinline__ float tanh_fast(float x) {
    // tanh(x) = 2/(1+e^(-2x)) - 1; saturates correctly at +-1
    return __builtin_amdgcn_rcpf(1.0f + __expf(-2.0f * x)) * 2.0f - 1.0f;
}

// One LSTM cell step for a single element held in registers.
// Weight/bias accesses use wave-uniform addresses -> backend emits s_load
// (scalar K$ path), so weights cost zero VALU/LDS bandwidth.
__device__ __forceinline__ void lstm_cell_step(
    float x0, float x1,
    float h[HID], float c[HID],
    const float* __restrict__ Wih,  // (32,2) row-major
    const float* __restrict__ Whh,  // (32,8) row-major
    const float* __restrict__ bih,  // (32,)
    const float* __restrict__ bhh)  // (32,)
{
    float hn[HID];
#pragma unroll
    for (int k = 0; k < HID; ++k) {
        // gate rows: i=k, f=k+8, g=k+16, o=k+24 (torch LSTMCell order)
        float gi = bih[k]      + bhh[k];
        float gf = bih[k + 8]  + bhh[k + 8];
        float gg = bih[k + 16] + bhh[k + 16];
        float go = bih[k + 24] + bhh[k + 24];

        gi += Wih[(k)      * 2 + 0] * x0 + Wih[(k)      * 2 + 1] * x1;
        gf += Wih[(k + 8)  * 2 + 0] * x0 + Wih[(k + 8)  * 2 + 1] * x1;
        gg += Wih[(k + 16) * 2 + 0] * x0 + Wih[(k + 16) * 2 + 1] * x1;
        go += Wih[(k + 24) * 2 + 0] * x0 + Wih[(k + 24) * 2 + 1] * x1;

#pragma unroll
        for (int j = 0; j < HID; ++j) {
            float hj = h[j];
            gi += Whh[(k)      * HID + j] * hj;
            gf += Whh[(k + 8)  * HID + j] * hj;
            gg += Whh[(k + 16) * HID + j] * hj;
            go += Whh[(k + 24) * HID + j] * hj;
        }

        gi = sigmoid_fast(gi);
        gf = sigmoid_fast(gf);
        gg = tanh_fast(gg);
        go = sigmoid_fast(go);

        float cn = gf * c[k] + gi * gg;
        c[k]  = cn;
        hn[k] = go * tanh_fast(cn);
    }
#pragma unroll
    for (int k = 0; k < HID; ++k) h[k] = hn[k];
}

__global__ __launch_bounds__(256) void MYLSTM_88201448390683_kernel(
    const float* __restrict__ obs,    // (OBS_LEN, B, 2)
    const float* __restrict__ h0,     // (B, HID)
    const float* __restrict__ c0,     // (B, HID)
    const float* __restrict__ Wih_t, const float* __restrict__ Whh_t,
    const float* __restrict__ bih_t, const float* __restrict__ bhh_t,
    const float* __restrict__ Wih_p, const float* __restrict__ Whh_p,
    const float* __restrict__ bih_p, const float* __restrict__ bhh_p,
    const float* __restrict__ Wp,     // (2, HID)
    const float* __restrict__ bp,     // (2,)
    float* __restrict__ out,          // (PRED_LEN, B, 2)
    int B)
{
    const int b = blockIdx.x * blockDim.x + threadIdx.x;
    if (b >= B) return;

    float h[HID], c[HID];
    // (B,8) fp32 -> two float4 loads each, 32B-aligned per thread
    {
        const float4* h4 = reinterpret_cast<const float4*>(h0 + (size_t)b * HID);
        const float4* c4 = reinterpret_cast<const float4*>(c0 + (size_t)b * HID);
        float4 ha = h4[0], hb = h4[1];
        float4 ca = c4[0], cb = c4[1];
        h[0] = ha.x; h[1] = ha.y; h[2] = ha.z; h[3] = ha.w;
        h[4] = hb.x; h[5] = hb.y; h[6] = hb.z; h[7] = hb.w;
        c[0] = ca.x; c[1] = ca.y; c[2] = ca.z; c[3] = ca.w;
        c[4] = cb.x; c[5] = cb.y; c[6] = cb.z; c[7] = cb.w;
    }

    // ---- encoder: 8 steps, x = relu(obs[t]) ----
#pragma unroll 1
    for (int t = 0; t < OBS_LEN; ++t) {
        float2 xv = *reinterpret_cast<const float2*>(obs + ((size_t)t * B + b) * 2);
        float x0 = fmaxf(xv.x, 0.0f);
        float x1 = fmaxf(xv.y, 0.0f);
        lstm_cell_step(x0, x1, h, c, Wih_t, Whh_t, bih_t, bhh_t);
    }

    // ---- decoder: h carries over, c reset to 0, x = previous output ----
#pragma unroll
    for (int k = 0; k < HID; ++k) c[k] = 0.0f;
    float o0 = 0.0f, o1 = 0.0f;

#pragma unroll 1
    for (int t = 0; t < PRED_LEN; ++t) {
        lstm_cell_step(o0, o1, h, c, Wih_p, Whh_p, bih_p, bhh_p);
        // out = tanh(h @ Wp.T + bp) * SCALE ; Wp is (2, HID) row-major
        float a0 = bp[0], a1 = bp[1];
#pragma unroll
        for (int j = 0; j < HID; ++j) {
            a0 += Wp[j] * h[j];
            a1 += Wp[HID + j] * h[j];
        }
        o0 = tanh_fast(a0) * SCALE;
        o1 = tanh_fast(a1) * SCALE;
        *reinterpret_cast<float2*>(out + ((size_t)t * B + b) * 2) = make_float2(o0, o1);
    }
}

extern "C" void kernel_launch(void* const* d_in, const int* in_sizes, int n_in,
                              void* d_out, int out_size, void* d_ws, size_t ws_size,
                              hipStream_t stream) {
    const float* obs   = (const float*)d_in[0];
    const float* h0    = (const float*)d_in[1];
    const float* c0    = (const float*)d_in[2];
    const float* Wih_t = (const float*)d_in[3];
    const float* Whh_t = (const float*)d_in[4];
    const float* bih_t = (const float*)d_in[5];
    const float* bhh_t = (const float*)d_in[6];
    const float* Wih_p = (const float*)d_in[7];
    const float* Whh_p = (const float*)d_in[8];
    const float* bih_p = (const float*)d_in[9];
    const float* bhh_p = (const float*)d_in[10];
    const float* Wp    = (const float*)d_in[11];
    const float* bp    = (const float*)d_in[12];
    float* out = (float*)d_out;

    const int B = in_sizes[1] / HID;  // h0 is (B, HID)
    const int block = 256;
    const int grid = (B + block - 1) / block;

    hipLaunchKernelGGL(MYLSTM_88201448390683_kernel, dim3(grid), dim3(block), 0, stream,
                       obs, h0, c0,
                       Wih_t, Whh_t, bih_t, bhh_t,
                       Wih_p, Whh_p, bih_p, bhh_p,
                       Wp, bp, out, B);
}

// Round 2
// 862.159 us; speedup vs baseline: 1.1159x; 1.1159x over previous
//
#include <hip/hip_runtime.h>

#define HID 8
#define OBS_LEN 8
#define PRED_LEN 12
#define SCALE 4.4f
#define ELEMS 4
#define BLOCK 256

// Fast device math: v_exp_f32 + v_rcp_f32 (~1-2 ulp, far inside 2.6e-3 absmax threshold).
__device__ __forceinline__ float sigmoid_fast(float x) {
    return __builtin_amdgcn_rcpf(1.0f + __expf(-x));
}
__device__ __forceinline__ float tanh_fast(float x) {
    return __builtin_amdgcn_rcpf(1.0f + __expf(-2.0f * x)) * 2.0f - 1.0f;
}

// LSTM cell step for ELEMS batch elements per thread.
// Each weight (uniform -> s_load / SGPR operand) feeds ELEMS FMAs, amortizing
// the per-weight access overhead that dominated the 1-elem/thread version.
__device__ __forceinline__ void cell_step(
    const float x0[ELEMS], const float x1[ELEMS],
    float h[ELEMS][HID], float c[ELEMS][HID],
    const float* __restrict__ Wih,   // (32,2) row-major
    const float* __restrict__ Whh,   // (32,8) row-major
    const float* __restrict__ bih,   // (32,)
    const float* __restrict__ bhh)   // (32,)
{
    float hn[ELEMS][HID];
#pragma unroll
    for (int k = 0; k < HID; ++k) {
        // gate rows: i=k, f=k+8, g=k+16, o=k+24 (torch LSTMCell order)
        const float bi = bih[k]      + bhh[k];
        const float bf = bih[k + 8]  + bhh[k + 8];
        const float bg = bih[k + 16] + bhh[k + 16];
        const float bo = bih[k + 24] + bhh[k + 24];
        const float wi0 = Wih[(k)      * 2 + 0], wi1 = Wih[(k)      * 2 + 1];
        const float wf0 = Wih[(k + 8)  * 2 + 0], wf1 = Wih[(k + 8)  * 2 + 1];
        const float wg0 = Wih[(k + 16) * 2 + 0], wg1 = Wih[(k + 16) * 2 + 1];
        const float wo0 = Wih[(k + 24) * 2 + 0], wo1 = Wih[(k + 24) * 2 + 1];

        float gi[ELEMS], gf[ELEMS], gg[ELEMS], go[ELEMS];
#pragma unroll
        for (int i = 0; i < ELEMS; ++i) {
            gi[i] = bi + wi0 * x0[i] + wi1 * x1[i];
            gf[i] = bf + wf0 * x0[i] + wf1 * x1[i];
            gg[i] = bg + wg0 * x0[i] + wg1 * x1[i];
            go[i] = bo + wo0 * x0[i] + wo1 * x1[i];
        }
#pragma unroll
        for (int j = 0; j < HID; ++j) {
            const float wji = Whh[(k)      * HID + j];
            const float wjf = Whh[(k + 8)  * HID + j];
            const float wjg = Whh[(k + 16) * HID + j];
            const float wjo = Whh[(k + 24) * HID + j];
#pragma unroll
            for (int i = 0; i < ELEMS; ++i) {
                const float hj = h[i][j];
                gi[i] += wji * hj;
                gf[i] += wjf * hj;
                gg[i] += wjg * hj;
                go[i] += wjo * hj;
            }
        }
#pragma unroll
        for (int i = 0; i < ELEMS; ++i) {
            const float ii = sigmoid_fast(gi[i]);
            const float ff = sigmoid_fast(gf[i]);
            const float g2 = tanh_fast(gg[i]);
            const float oo = sigmoid_fast(go[i]);
            const float cn = ff * c[i][k] + ii * g2;
            c[i][k]  = cn;
            hn[i][k] = oo * tanh_fast(cn);
        }
    }
#pragma unroll
    for (int i = 0; i < ELEMS; ++i)
#pragma unroll
        for (int k = 0; k < HID; ++k) h[i][k] = hn[i][k];
}

__global__ __launch_bounds__(BLOCK) void MYLSTM_88201448390683_kernel(
    const float* __restrict__ obs,    // (OBS_LEN, B, 2)
    const float* __restrict__ h0,     // (B, HID)
    const float* __restrict__ c0,     // (B, HID)
    const float* __restrict__ Wih_t, const float* __restrict__ Whh_t,
    const float* __restrict__ bih_t, const float* __restrict__ bhh_t,
    const float* __restrict__ Wih_p, const float* __restrict__ Whh_p,
    const float* __restrict__ bih_p, const float* __restrict__ bhh_p,
    const float* __restrict__ Wp,     // (2, HID)
    const float* __restrict__ bp,     // (2,)
    float* __restrict__ out,          // (PRED_LEN, B, 2)
    int B)
{
    // thread handles elements base + i*BLOCK (coalesced within the wave)
    const int base = blockIdx.x * (BLOCK * ELEMS) + threadIdx.x;

    int  e[ELEMS];
    bool ok[ELEMS];
#pragma unroll
    for (int i = 0; i < ELEMS; ++i) {
        const int ei = base + i * BLOCK;
        ok[i] = ei < B;
        e[i]  = ok[i] ? ei : 0;   // clamp for safe loads; stores predicated
    }

    float h[ELEMS][HID], c[ELEMS][HID];
#pragma unroll
    for (int i = 0; i < ELEMS; ++i) {
        const float4* h4 = reinterpret_cast<const float4*>(h0 + (size_t)e[i] * HID);
        const float4* c4 = reinterpret_cast<const float4*>(c0 + (size_t)e[i] * HID);
        const float4 ha = h4[0], hb = h4[1];
        const float4 ca = c4[0], cb = c4[1];
        h[i][0] = ha.x; h[i][1] = ha.y; h[i][2] = ha.z; h[i][3] = ha.w;
        h[i][4] = hb.x; h[i][5] = hb.y; h[i][6] = hb.z; h[i][7] = hb.w;
        c[i][0] = ca.x; c[i][1] = ca.y; c[i][2] = ca.z; c[i][3] = ca.w;
        c[i][4] = cb.x; c[i][5] = cb.y; c[i][6] = cb.z; c[i][7] = cb.w;
    }

    // ---- encoder: 8 steps, x = relu(obs[t]) ----
#pragma unroll 1
    for (int t = 0; t < OBS_LEN; ++t) {
        float x0[ELEMS], x1[ELEMS];
#pragma unroll
        for (int i = 0; i < ELEMS; ++i) {
            const float2 xv = *reinterpret_cast<const float2*>(obs + ((size_t)t * B + e[i]) * 2);
            x0[i] = fmaxf(xv.x, 0.0f);
            x1[i] = fmaxf(xv.y, 0.0f);
        }
        cell_step(x0, x1, h, c, Wih_t, Whh_t, bih_t, bhh_t);
    }

    // ---- decoder: h carries over, c reset to 0, x = previous output ----
#pragma unroll
    for (int i = 0; i < ELEMS; ++i)
#pragma unroll
        for (int k = 0; k < HID; ++k) c[i][k] = 0.0f;

    // hoist projection weights (18 uniform values -> SGPRs) out of the time loop
    float wpa[HID], wpb[HID];
#pragma unroll
    for (int j = 0; j < HID; ++j) { wpa[j] = Wp[j]; wpb[j] = Wp[HID + j]; }
    const float bp0 = bp[0], bp1 = bp[1];

    float o0[ELEMS], o1[ELEMS];
#pragma unroll
    for (int i = 0; i < ELEMS; ++i) { o0[i] = 0.0f; o1[i] = 0.0f; }

#pragma unroll 1
    for (int t = 0; t < PRED_LEN; ++t) {
        cell_step(o0, o1, h, c, Wih_p, Whh_p, bih_p, bhh_p);
#pragma unroll
        for (int i = 0; i < ELEMS; ++i) {
            float a0 = bp0, a1 = bp1;
#pragma unroll
            for (int j = 0; j < HID; ++j) {
                a0 += wpa[j] * h[i][j];
                a1 += wpb[j] * h[i][j];
            }
            o0[i] = tanh_fast(a0) * SCALE;
            o1[i] = tanh_fast(a1) * SCALE;
            if (ok[i]) {
                *reinterpret_cast<float2*>(out + ((size_t)t * B + e[i]) * 2) =
                    make_float2(o0[i], o1[i]);
            }
        }
    }
}

extern "C" void kernel_launch(void* const* d_in, const int* in_sizes, int n_in,
                              void* d_out, int out_size, void* d_ws, size_t ws_size,
                              hipStream_t stream) {
    const float* obs   = (const float*)d_in[0];
    const float* h0    = (const float*)d_in[1];
    const float* c0    = (const float*)d_in[2];
    const float* Wih_t = (const float*)d_in[3];
    const float* Whh_t = (const float*)d_in[4];
    const float* bih_t = (const float*)d_in[5];
    const float* bhh_t = (const float*)d_in[6];
    const float* Wih_p = (const float*)d_in[7];
    const float* Whh_p = (const float*)d_in[8];
    const float* bih_p = (const float*)d_in[9];
    const float* bhh_p = (const float*)d_in[10];
    const float* Wp    = (const float*)d_in[11];
    const float* bp    = (const float*)d_in[12];
    float* out = (float*)d_out;

    const int B = in_sizes[1] / HID;  // h0 is (B, HID)
    const int grid = (B + BLOCK * ELEMS - 1) / (BLOCK * ELEMS);

    hipLaunchKernelGGL(MYLSTM_88201448390683_kernel, dim3(grid), dim3(BLOCK), 0, stream,
                       obs, h0, c0,
                       Wih_t, Whh_t, bih_t, bhh_t,
                       Wih_p, Whh_p, bih_p, bhh_p,
                       Wp, bp, out, B);
}

// Round 3
// 399.618 us; speedup vs baseline: 2.4076x; 2.1575x over previous
//
#include <hip/hip_runtime.h>

#define HID 8
#define OBS_LEN 8
#define PRED_LEN 12
#define SCALE 4.4f
#define BLOCK 256
#define ELEMS_PER_BLOCK 128   // 4 waves * 32 elems per wave

typedef __attribute__((ext_vector_type(8)))  _Float16 half8;
typedef __attribute__((ext_vector_type(16))) float    f32x16;

// Fast activations (validated R1/R2: absmax 9.8e-4 vs 2.6e-3 threshold)
__device__ __forceinline__ float sigmoid_fast(float x) {
    return __builtin_amdgcn_rcpf(1.0f + __expf(-x));
}
__device__ __forceinline__ float tanh_fast(float x) {
    return __builtin_amdgcn_rcpf(1.0f + __expf(-2.0f * x)) * 2.0f - 1.0f;
}

struct AB { half8 hi, lo; };

// fp32 -> f16 hi/lo split (hi RNE cvt, lo = residual; combined ~2^-23 relative)
__device__ __forceinline__ AB split8(const float v[8]) {
    AB r;
#pragma unroll
    for (int i = 0; i < 8; ++i) {
        _Float16 h = (_Float16)v[i];
        r.hi[i] = h;
        r.lo[i] = (_Float16)(v[i] - (float)h);
    }
    return r;
}

// A operand (weights, built once per phase, lives in 8 VGPRs):
// W[m][k] over K=16: k0,k1 = Wih[m][0:2]; k2..k9 = Whh[m][0:8]; k10 = bias[m]
// (paired with constant-1.0 row in B); k11..15 = 0.
// Lane L supplies A[m = L&31][k = 8*(L>>5) + i], i=0..7.
__device__ __forceinline__ AB build_A(int m, int half,
    const float* __restrict__ Wih, const float* __restrict__ Whh,
    const float* __restrict__ bih, const float* __restrict__ bhh)
{
    const float b = bih[m] + bhh[m];
    const float wih0 = Wih[m * 2 + 0], wih1 = Wih[m * 2 + 1];
    float whh[8];
#pragma unroll
    for (int j = 0; j < 8; ++j) whh[j] = Whh[m * 8 + j];
    float w[8];
    w[0] = half ? whh[6] : wih0;
    w[1] = half ? whh[7] : wih1;
    w[2] = half ? b      : whh[0];
    w[3] = half ? 0.0f   : whh[1];
    w[4] = half ? 0.0f   : whh[2];
    w[5] = half ? 0.0f   : whh[3];
    w[6] = half ? 0.0f   : whh[4];
    w[7] = half ? 0.0f   : whh[5];
    return split8(w);
}

// B operand (inputs, rebuilt each step):
// column n = elem = L&31; rows k = 8*(L>>5)+i.
// half0 rows 0..7:  [x0, x1, h0, h1, h2, h3, h4, h5]
// half1 rows 8..15: [h6, h7, 1.0(bias row), 0, 0, 0, 0, 0]
// Lane holds h for its 4 units (half0: units 0-3, half1: units 4-7);
// h4,h5 come from the partner lane via shfl_xor(32).
__device__ __forceinline__ AB build_B(float x0, float x1, const float h[4], int half) {
    const float p0 = __shfl_xor(h[0], 32);  // half0 receives partner's unit-4
    const float p1 = __shfl_xor(h[1], 32);  // half0 receives partner's unit-5
    float v[8];
    v[0] = half ? h[2] : x0;     // h6 : x0
    v[1] = half ? h[3] : x1;     // h7 : x1
    v[2] = half ? 1.0f : h[0];   // bias row : h0
    v[3] = half ? 0.0f : h[1];
    v[4] = half ? 0.0f : h[2];
    v[5] = half ? 0.0f : h[3];
    v[6] = half ? 0.0f : p0;     // h4
    v[7] = half ? 0.0f : p1;     // h5
    return split8(v);
}

// One LSTM step for 32 elements per wave.
// D[row=gate][col=elem]: lane L -> elem L&31; reg j -> row (j&3)+8*(j>>2)+4*(L>>5)
// => reg j&3 = unit (within this lane's 4 units), j>>2 = gate class (i,f,g,o).
__device__ __forceinline__ void lstm_mfma_step(const AB& A, const AB& B,
                                               float c[4], float h[4]) {
    f32x16 acc = {};
    acc = __builtin_amdgcn_mfma_f32_32x32x16_f16(A.hi, B.hi, acc, 0, 0, 0);
    acc = __builtin_amdgcn_mfma_f32_32x32x16_f16(A.hi, B.lo, acc, 0, 0, 0);
    acc = __builtin_amdgcn_mfma_f32_32x32x16_f16(A.lo, B.hi, acc, 0, 0, 0);
#pragma unroll
    for (int j = 0; j < 4; ++j) {
        const float ig = sigmoid_fast(acc[j]);
        const float fg = sigmoid_fast(acc[4 + j]);
        const float gg = tanh_fast(acc[8 + j]);
        const float og = sigmoid_fast(acc[12 + j]);
        const float cn = fg * c[j] + ig * gg;
        c[j] = cn;
        h[j] = og * tanh_fast(cn);
    }
}

__global__ __launch_bounds__(BLOCK) void MYLSTM_88201448390683_kernel(
    const float* __restrict__ obs,    // (OBS_LEN, B, 2)
    const float* __restrict__ h0,     // (B, HID)
    const float* __restrict__ c0,     // (B, HID)
    const float* __restrict__ Wih_t, const float* __restrict__ Whh_t,
    const float* __restrict__ bih_t, const float* __restrict__ bhh_t,
    const float* __restrict__ Wih_p, const float* __restrict__ Whh_p,
    const float* __restrict__ bih_p, const float* __restrict__ bhh_p,
    const float* __restrict__ Wp,     // (2, HID)
    const float* __restrict__ bp,     // (2,)
    float* __restrict__ out,          // (PRED_LEN, B, 2)
    int B)
{
    const int lane = threadIdx.x & 63;
    const int wid  = threadIdx.x >> 6;
    const int e    = lane & 31;         // element column within tile; also gate row m
    const int half = lane >> 5;

    int eg = blockIdx.x * ELEMS_PER_BLOCK + wid * 32 + e;
    const bool ok = eg < B;
    if (!ok) eg = 0;

    // state: this lane owns units 4*half .. 4*half+3 of element eg
    float h[4], c[4];
    {
        const float4 hv = *reinterpret_cast<const float4*>(h0 + (size_t)eg * HID + half * 4);
        const float4 cv = *reinterpret_cast<const float4*>(c0 + (size_t)eg * HID + half * 4);
        h[0] = hv.x; h[1] = hv.y; h[2] = hv.z; h[3] = hv.w;
        c[0] = cv.x; c[1] = cv.y; c[2] = cv.z; c[3] = cv.w;
    }

    // ---- encoder ----
    {
        const AB Aenc = build_A(e, half, Wih_t, Whh_t, bih_t, bhh_t);
#pragma unroll 1
        for (int t = 0; t < OBS_LEN; ++t) {
            const float2 xv = *reinterpret_cast<const float2*>(obs + ((size_t)t * B + eg) * 2);
            const AB Bv = build_B(fmaxf(xv.x, 0.0f), fmaxf(xv.y, 0.0f), h, half);
            lstm_mfma_step(Aenc, Bv, c, h);
        }
    }

    // ---- decoder ----
    const AB Adec = build_A(e, half, Wih_p, Whh_p, bih_p, bhh_p);
#pragma unroll
    for (int j = 0; j < 4; ++j) c[j] = 0.0f;

    // projection weights for this lane's 4 units (loaded once)
    float wa[4], wb[4];
#pragma unroll
    for (int j = 0; j < 4; ++j) {
        wa[j] = Wp[4 * half + j];
        wb[j] = Wp[HID + 4 * half + j];
    }
    const float bp0 = bp[0], bp1 = bp[1];

    float x0 = 0.0f, x1 = 0.0f;
#pragma unroll 1
    for (int t = 0; t < PRED_LEN; ++t) {
        const AB Bv = build_B(x0, x1, h, half);
        lstm_mfma_step(Adec, Bv, c, h);
        // out = tanh(h @ Wp.T + bp) * SCALE ; h split across lane pairs
        float a0 = wa[0] * h[0] + wa[1] * h[1] + wa[2] * h[2] + wa[3] * h[3];
        float a1 = wb[0] * h[0] + wb[1] * h[1] + wb[2] * h[2] + wb[3] * h[3];
        a0 += __shfl_xor(a0, 32);
        a1 += __shfl_xor(a1, 32);
        x0 = tanh_fast(a0 + bp0) * SCALE;
        x1 = tanh_fast(a1 + bp1) * SCALE;
        if (!half && ok) {
            *reinterpret_cast<float2*>(out + ((size_t)t * B + eg) * 2) = make_float2(x0, x1);
        }
    }
}

extern "C" void kernel_launch(void* const* d_in, const int* in_sizes, int n_in,
                              void* d_out, int out_size, void* d_ws, size_t ws_size,
                              hipStream_t stream) {
    const float* obs   = (const float*)d_in[0];
    const float* h0    = (const float*)d_in[1];
    const float* c0    = (const float*)d_in[2];
    const float* Wih_t = (const float*)d_in[3];
    const float* Whh_t = (const float*)d_in[4];
    const float* bih_t = (const float*)d_in[5];
    const float* bhh_t = (const float*)d_in[6];
    const float* Wih_p = (const float*)d_in[7];
    const float* Whh_p = (const float*)d_in[8];
    const float* bih_p = (const float*)d_in[9];
    const float* bhh_p = (const float*)d_in[10];
    const float* Wp    = (const float*)d_in[11];
    const float* bp    = (const float*)d_in[12];
    float* out = (float*)d_out;

    const int B = in_sizes[1] / HID;  // h0 is (B, HID)
    const int grid = (B + ELEMS_PER_BLOCK - 1) / ELEMS_PER_BLOCK;

    hipLaunchKernelGGL(MYLSTM_88201448390683_kernel, dim3(grid), dim3(BLOCK), 0, stream,
                       obs, h0, c0,
                       Wih_t, Whh_t, bih_t, bhh_t,
                       Wih_p, Whh_p, bih_p, bhh_p,
                       Wp, bp, out, B);
}

// Round 5
// 365.183 us; speedup vs baseline: 2.6346x; 1.0943x over previous
//
#include <hip/hip_runtime.h>

#define HID 8
#define OBS_LEN 8
#define PRED_LEN 12
#define SCALE 4.4f
#define BLOCK 256
#define ELEMS_PER_BLOCK 128   // 4 waves * 32 elems per wave

typedef __attribute__((ext_vector_type(8)))  _Float16 half8;
typedef __attribute__((ext_vector_type(16))) float    f32x16;

#define LOG2E 1.44269504f

struct AB { half8 hi, lo; };
struct H2 { _Float16 hi, lo; };

// fp32 -> f16 hi/lo split (residual lo makes hi+lo exact to ~2^-23 rel)
__device__ __forceinline__ H2 split1(float v) {
    H2 r;
    r.hi = (_Float16)v;
    r.lo = (_Float16)(v - (float)r.hi);
    return r;
}

// Pair-batched reciprocal: 1 v_rcp + 3 v_mul for two values.
// Pairs (not quads): quad denominator products can overflow f32.
__device__ __forceinline__ void inv_pair(float a, float b, float& ia, float& ib) {
    const float r = __builtin_amdgcn_rcpf(a * b);
    ia = r * b;
    ib = r * a;
}

// A operand, built once per phase. MFMA sums over k, so k-rows are ordered to
// make B's per-lane pattern IDENTICAL for both half-waves (no selects/shfl in
// the per-step B build):
//   B rows (half p, lane-local): k=8p+{0..7} = {x0, x1, h[4p+0..4p+3], 1, 0}
//   A rows: p0: {Wih[m][0], Wih[m][1], Whh[m][0..3], bias[m], 0}
//           p1: {0,         0,         Whh[m][4..7], 0,       0}
// x and the 1-row appear in both halves of B; A zeros the p1 copies.
__device__ __forceinline__ AB build_A(int m, int half,
    const float* __restrict__ Wih, const float* __restrict__ Whh,
    const float* __restrict__ bih, const float* __restrict__ bhh)
{
    float w[8];
    if (half == 0) {
        w[0] = Wih[m * 2 + 0];
        w[1] = Wih[m * 2 + 1];
        w[2] = Whh[m * 8 + 0];
        w[3] = Whh[m * 8 + 1];
        w[4] = Whh[m * 8 + 2];
        w[5] = Whh[m * 8 + 3];
        w[6] = bih[m] + bhh[m];
        w[7] = 0.0f;
    } else {
        w[0] = 0.0f;
        w[1] = 0.0f;
        w[2] = Whh[m * 8 + 4];
        w[3] = Whh[m * 8 + 5];
        w[4] = Whh[m * 8 + 6];
        w[5] = Whh[m * 8 + 7];
        w[6] = 0.0f;
        w[7] = 0.0f;
    }
    AB r;
#pragma unroll
    for (int i = 0; i < 8; ++i) {
        const H2 s = split1(w[i]);
        r.hi[i] = s.hi;
        r.lo[i] = s.lo;
    }
    return r;
}

// B operand: uniform across halves — no cndmask, no shfl, constants exact.
__device__ __forceinline__ AB build_B(float x0, float x1, const float h[4]) {
    AB r;
    const float v[6] = { x0, x1, h[0], h[1], h[2], h[3] };
#pragma unroll
    for (int i = 0; i < 6; ++i) {
        const H2 s = split1(v[i]);
        r.hi[i] = s.hi;
        r.lo[i] = s.lo;
    }
    r.hi[6] = (_Float16)1.0f; r.lo[6] = (_Float16)0.0f;
    r.hi[7] = (_Float16)0.0f; r.lo[7] = (_Float16)0.0f;
    return r;
}

// Pointwise LSTM combine in rational form (rcp-minimized):
//   sigma(a) = 1/(1+e^-a), tanh(g) = (1-e^-2g)/(1+e^-2g)
//   cn = c/uf + tg/(ui*vg) = (c*ui*vg + tg*uf) / (uf*ui*vg)   -> 1 rcp
//   h  = (1-ec) / (uo*(1+ec))                                  -> 1 rcp
// Remaining rcps pair-batched across units.
__device__ __forceinline__ void lstm_pointwise(const f32x16& acc, float c[4], float h[4]) {
    float num1[4], den1[4], uo[4];
#pragma unroll
    for (int j = 0; j < 4; ++j) {
        const float ai = acc[j], af = acc[4 + j], ag = acc[8 + j], ao = acc[12 + j];
        const float ei = __builtin_amdgcn_exp2f(ai * -LOG2E);
        const float ef = __builtin_amdgcn_exp2f(af * -LOG2E);
        const float eg = __builtin_amdgcn_exp2f(ag * (-2.0f * LOG2E));
        const float eo = __builtin_amdgcn_exp2f(ao * -LOG2E);
        const float ui = 1.0f + ei, uf = 1.0f + ef, vg = 1.0f + eg;
        const float tg = 1.0f - eg;
        const float uiv = ui * vg;
        num1[j] = fmaf(tg, uf, c[j] * uiv);
        den1[j] = uf * uiv;
        uo[j] = 1.0f + eo;
    }
    float inv1[4];
    inv_pair(den1[0], den1[1], inv1[0], inv1[1]);
    inv_pair(den1[2], den1[3], inv1[2], inv1[3]);

    float den2[4], tc[4];
#pragma unroll
    for (int j = 0; j < 4; ++j) {
        const float cn = num1[j] * inv1[j];
        c[j] = cn;
        // clamp: cn is the only unbounded recurrent quantity; cap exp2 arg at 43
        // (tanh saturated to ~1-1e-13 anyway; keeps den2 pair-product finite)
        const float s = fminf(cn * (-2.0f * LOG2E), 43.0f);
        const float ec = __builtin_amdgcn_exp2f(s);
        den2[j] = uo[j] * (1.0f + ec);
        tc[j] = 1.0f - ec;
    }
    float inv2[4];
    inv_pair(den2[0], den2[1], inv2[0], inv2[1]);
    inv_pair(den2[2], den2[3], inv2[2], inv2[3]);
#pragma unroll
    for (int j = 0; j < 4; ++j) h[j] = tc[j] * inv2[j];
}

__device__ __forceinline__ void lstm_mfma_step(const AB& A, const AB& B,
                                               float c[4], float h[4]) {
    f32x16 acc = {};
    acc = __builtin_amdgcn_mfma_f32_32x32x16_f16(A.hi, B.hi, acc, 0, 0, 0);
    acc = __builtin_amdgcn_mfma_f32_32x32x16_f16(A.hi, B.lo, acc, 0, 0, 0);
    acc = __builtin_amdgcn_mfma_f32_32x32x16_f16(A.lo, B.hi, acc, 0, 0, 0);
    lstm_pointwise(acc, c, h);
}

__global__ __launch_bounds__(BLOCK) void MYLSTM_88201448390683_kernel(
    const float* __restrict__ obs,    // (OBS_LEN, B, 2)
    const float* __restrict__ h0,     // (B, HID)
    const float* __restrict__ c0,     // (B, HID)
    const float* __restrict__ Wih_t, const float* __restrict__ Whh_t,
    const float* __restrict__ bih_t, const float* __restrict__ bhh_t,
    const float* __restrict__ Wih_p, const float* __restrict__ Whh_p,
    const float* __restrict__ bih_p, const float* __restrict__ bhh_p,
    const float* __restrict__ Wp,     // (2, HID)
    const float* __restrict__ bp,     // (2,)
    float* __restrict__ out,          // (PRED_LEN, B, 2)
    int B)
{
    const int lane = threadIdx.x & 63;
    const int wid  = threadIdx.x >> 6;
    const int e    = lane & 31;         // element column; also gate row m for A
    const int half = lane >> 5;

    int eg = blockIdx.x * ELEMS_PER_BLOCK + wid * 32 + e;
    const bool ok = eg < B;
    if (!ok) eg = 0;

    // lane owns units 4*half .. 4*half+3 of element eg (matches C/D layout:
    // row = (reg&3) + 8*(reg>>2) + 4*half => unit=(reg&3)+4*half, gate=reg>>2)
    float h[4], c[4];
    {
        const float4 hv = *reinterpret_cast<const float4*>(h0 + (size_t)eg * HID + half * 4);
        const float4 cv = *reinterpret_cast<const float4*>(c0 + (size_t)eg * HID + half * 4);
        h[0] = hv.x; h[1] = hv.y; h[2] = hv.z; h[3] = hv.w;
        c[0] = cv.x; c[1] = cv.y; c[2] = cv.z; c[3] = cv.w;
    }

    // ---- encoder ----
    {
        const AB Aenc = build_A(e, half, Wih_t, Whh_t, bih_t, bhh_t);
#pragma unroll 1
        for (int t = 0; t < OBS_LEN; ++t) {
            // both halves load the same element's obs (same address; L1 serves it)
            const float2 xv = *reinterpret_cast<const float2*>(obs + ((size_t)t * B + eg) * 2);
            const AB Bv = build_B(fmaxf(xv.x, 0.0f), fmaxf(xv.y, 0.0f), h);
            lstm_mfma_step(Aenc, Bv, c, h);
        }
    }

    // ---- decoder ----
    const AB Adec = build_A(e, half, Wih_p, Whh_p, bih_p, bhh_p);
#pragma unroll
    for (int j = 0; j < 4; ++j) c[j] = 0.0f;

    float wa[4], wb[4];
#pragma unroll
    for (int j = 0; j < 4; ++j) {
        wa[j] = Wp[4 * half + j];
        wb[j] = Wp[HID + 4 * half + j];
    }
    const float bp0 = bp[0], bp1 = bp[1];

    float x0 = 0.0f, x1 = 0.0f;
#pragma unroll 1
    for (int t = 0; t < PRED_LEN; ++t) {
        const AB Bv = build_B(x0, x1, h);
        lstm_mfma_step(Adec, Bv, c, h);
        // out = tanh(h @ Wp.T + bp) * SCALE ; h split across lane pairs
        float a0 = wa[0] * h[0] + wa[1] * h[1] + wa[2] * h[2] + wa[3] * h[3];
        float a1 = wb[0] * h[0] + wb[1] * h[1] + wb[2] * h[2] + wb[3] * h[3];
        a0 += __shfl_xor(a0, 32);   // both halves now hold the full sums
        a1 += __shfl_xor(a1, 32);
        a0 += bp0; a1 += bp1;
        // tanh via rational form, rcps pair-batched
        const float e0 = __builtin_amdgcn_exp2f(a0 * (-2.0f * LOG2E));
        const float e1 = __builtin_amdgcn_exp2f(a1 * (-2.0f * LOG2E));
        float i0, i1;
        inv_pair(1.0f + e0, 1.0f + e1, i0, i1);
        x0 = (1.0f - e0) * i0 * SCALE;
        x1 = (1.0f - e1) * i1 * SCALE;
        if (!half && ok) {
            *reinterpret_cast<float2*>(out + ((size_t)t * B + eg) * 2) = make_float2(x0, x1);
        }
    }
}

extern "C" void kernel_launch(void* const* d_in, const int* in_sizes, int n_in,
                              void* d_out, int out_size, void* d_ws, size_t ws_size,
                              hipStream_t stream) {
    const float* obs   = (const float*)d_in[0];
    const float* h0    = (const float*)d_in[1];
    const float* c0    = (const float*)d_in[2];
    const float* Wih_t = (const float*)d_in[3];
    const float* Whh_t = (const float*)d_in[4];
    const float* bih_t = (const float*)d_in[5];
    const float* bhh_t = (const float*)d_in[6];
    const float* Wih_p = (const float*)d_in[7];
    const float* Whh_p = (const float*)d_in[8];
    const float* bih_p = (const float*)d_in[9];
    const float* bhh_p = (const float*)d_in[10];
    const float* Wp    = (const float*)d_in[11];
    const float* bp    = (const float*)d_in[12];
    float* out = (float*)d_out;

    const int B = in_sizes[1] / HID;  // h0 is (B, HID)
    const int grid = (B + ELEMS_PER_BLOCK - 1) / ELEMS_PER_BLOCK;

    hipLaunchKernelGGL(MYLSTM_88201448390683_kernel, dim3(grid), dim3(BLOCK), 0, stream,
                       obs, h0, c0,
                       Wih_t, Whh_t, bih_t, bhh_t,
                       Wih_p, Whh_p, bih_p, bhh_p,
                       Wp, bp, out, B);
}